// Round 2
// baseline (311.732 us; speedup 1.0000x reference)
//
#include <hip/hip_runtime.h>
#include <hip/hip_bf16.h>

typedef __attribute__((ext_vector_type(8))) short bf16x8;
typedef __attribute__((ext_vector_type(4))) float f32x4;

#define HD 256   // hidden size
#define NB 32    // batch
#define NT 4096  // timesteps
#define NE 8192  // edges per graph
#define N2 512   // 2*H
#define LDA 264  // LDS row stride in shorts (256 + 8 pad)

static __device__ __forceinline__ unsigned short f2bf(float f) {
  unsigned int u = __float_as_uint(f);
  u += 0x7fff + ((u >> 16) & 1);  // round-to-nearest-even
  return (unsigned short)(u >> 16);
}

static __device__ __forceinline__ float fast_tanh(float x) {
  x = fminf(15.f, fmaxf(-15.f, x));
  float e = __expf(x + x);
  return (e - 1.f) * __builtin_amdgcn_rcpf(e + 1.f);
}

// c[b][n] = b_attn[n] + sum_k hidden[b][k] * W_attn[n][k]   (first H columns)
__global__ __launch_bounds__(256) void precompute_c(
    const float* __restrict__ hidden, const float* __restrict__ Wattn,
    const float* __restrict__ battn, float* __restrict__ cvec) {
  __shared__ float Ws[64 * 260];
  __shared__ float Hs[HD];
  const int tid = threadIdx.x;
  const int chunk = blockIdx.x & 7;
  const int b = blockIdx.x >> 3;
#pragma unroll
  for (int it = 0; it < 16; ++it) {
    int f = it * 1024 + tid * 4;
    int i = f >> 8, k = f & 255;
    float4 w4 = *(const float4*)(Wattn + (chunk * 64 + i) * N2 + k);
    *(float4*)&Ws[i * 260 + k] = w4;
  }
  if (tid < 64)
    *(float4*)&Hs[tid * 4] = *(const float4*)(hidden + b * HD + tid * 4);
  __syncthreads();
  const int nl = tid >> 2;
  const int kb = (tid & 3) * 64;
  float sum = 0.f;
#pragma unroll
  for (int z = 0; z < 64; z += 4) {
    float4 h4 = *(const float4*)&Hs[kb + z];
    float4 w4 = *(const float4*)&Ws[nl * 260 + kb + z];
    sum = fmaf(h4.x, w4.x, sum);
    sum = fmaf(h4.y, w4.y, sum);
    sum = fmaf(h4.z, w4.z, sum);
    sum = fmaf(h4.w, w4.w, sum);
  }
  sum += __shfl_xor(sum, 1, 64);
  sum += __shfl_xor(sum, 2, 64);
  if ((tid & 3) == 0)
    cvec[b * N2 + chunk * 64 + nl] = sum + battn[chunk * 64 + nl];
}

// scores[b][t] = sum_n v[n]*tanh(c[b][n] + sum_k enc[t*NB+b][k]*W2[n][k])
// One WG per 64 rows of enc_flat. MFMA 16x16x32 bf16; wave = 32 rows x 32 cols
// of each 64-col N-chunk (2x2 register blocking). Epilogue fuses tanh + v-dot.
// Waves (wr, wc) = (0,0),(0,32),(32,0),(32,32): two waves share each row range
// with different column halves -> combine partials through LDS at the end.
__global__ __launch_bounds__(256, 2) void score_gemm(
    const float* __restrict__ enc, const float* __restrict__ Wattn,
    const float* __restrict__ cvec, const float* __restrict__ vvec,
    float* __restrict__ scores) {
  __shared__ short As[64 * LDA];
  __shared__ short Bs[64 * LDA];
  __shared__ float part[2][64];
  const int tid = threadIdx.x;
  const int row0 = blockIdx.x * 64;
  const int w = tid >> 6;
  const int lane = tid & 63;
  const int q = lane >> 4;
  const int m = lane & 15;
  const int wr = 32 * (w >> 1);  // wave row offset within tile
  const int wc = 32 * (w & 1);   // wave col offset within N-chunk

  // ---- stage A tile (64 rows x 256 k) fp32 -> bf16 ----
  {
    const float* src = enc + (long)row0 * HD;
#pragma unroll
    for (int it = 0; it < 16; ++it) {
      int f = it * 1024 + tid * 4;
      float4 a4 = *(const float4*)(src + f);
      int i = f >> 8, k = f & 255;
      *(short4*)&As[i * LDA + k] = make_short4(
          (short)f2bf(a4.x), (short)f2bf(a4.y), (short)f2bf(a4.z), (short)f2bf(a4.w));
    }
  }

  float rowacc[2][4] = {};

  for (int nt = 0; nt < 8; ++nt) {
    __syncthreads();  // Bs free to overwrite; first iter: As staged
    // ---- stage B chunk (64 n-rows x 256 k) from W_attn[:, H:] ----
#pragma unroll
    for (int it = 0; it < 16; ++it) {
      int f = it * 1024 + tid * 4;
      int i = f >> 8, k = f & 255;
      float4 b4 = *(const float4*)(Wattn + (nt * 64 + i) * N2 + HD + k);
      *(short4*)&Bs[i * LDA + k] = make_short4(
          (short)f2bf(b4.x), (short)f2bf(b4.y), (short)f2bf(b4.z), (short)f2bf(b4.w));
    }
    __syncthreads();

    f32x4 acc00 = {}, acc01 = {}, acc10 = {}, acc11 = {};
#pragma unroll
    for (int kk = 0; kk < 8; ++kk) {
      const int ko = kk * 32 + q * 8;
      bf16x8 a0 = *(const bf16x8*)&As[(wr + m) * LDA + ko];
      bf16x8 a1 = *(const bf16x8*)&As[(wr + 16 + m) * LDA + ko];
      bf16x8 b0 = *(const bf16x8*)&Bs[(wc + m) * LDA + ko];
      bf16x8 b1 = *(const bf16x8*)&Bs[(wc + 16 + m) * LDA + ko];
      acc00 = __builtin_amdgcn_mfma_f32_16x16x32_bf16(a0, b0, acc00, 0, 0, 0);
      acc01 = __builtin_amdgcn_mfma_f32_16x16x32_bf16(a0, b1, acc01, 0, 0, 0);
      acc10 = __builtin_amdgcn_mfma_f32_16x16x32_bf16(a1, b0, acc10, 0, 0, 0);
      acc11 = __builtin_amdgcn_mfma_f32_16x16x32_bf16(a1, b1, acc11, 0, 0, 0);
    }

    // ---- epilogue: e = tanh(acc + c[b][n]); partial score += v[n]*e ----
    const int n0 = nt * 64 + wc + m;
    const float v0 = vvec[n0];
    const float v1 = vvec[n0 + 16];
#pragma unroll
    for (int i = 0; i < 2; ++i) {
      const f32x4 ac0 = i ? acc10 : acc00;
      const f32x4 ac1 = i ? acc11 : acc01;
      float ej[4];
#pragma unroll
      for (int j = 0; j < 4; ++j) {
        // C/D layout: row = 4*q + j (within 16-tile), col = m
        const int bb = (wr + 16 * i + 4 * q + j) & 31;  // row0 % 32 == 0
        float e0 = fast_tanh(ac0[j] + cvec[bb * N2 + n0]);
        float e1 = fast_tanh(ac1[j] + cvec[bb * N2 + n0 + 16]);
        ej[j] = e0 * v0 + e1 * v1;
      }
#pragma unroll
      for (int j = 0; j < 4; ++j) {
        float sv = ej[j];
        sv += __shfl_xor(sv, 1, 64);
        sv += __shfl_xor(sv, 2, 64);
        sv += __shfl_xor(sv, 4, 64);
        sv += __shfl_xor(sv, 8, 64);  // sum over 16 cols of the tile
        rowacc[i][j] += sv;
      }
    }
  }

  // combine the two column-half partials per row, then store
  if (m == 0) {
#pragma unroll
    for (int i = 0; i < 2; ++i)
#pragma unroll
      for (int j = 0; j < 4; ++j)
        part[w & 1][wr + 16 * i + 4 * q + j] = rowacc[i][j];
  }
  __syncthreads();
  if (tid < 64) {
    const int r = row0 + tid;  // flat row = t*NB + b
    scores[(r & 31) * NT + (r >> 5)] = part[0][tid] + part[1][tid];
  }
}

// Per batch row: softmax over T, then out[dst] += 0.1*w[src]*(dst != src+1)
__global__ __launch_bounds__(1024) void softmax_scatter(
    float* __restrict__ w, const int* __restrict__ esrc,
    const int* __restrict__ edst) {
  __shared__ float wsv[NT];
  __shared__ float asv[NT];
  __shared__ float rtmp[16];
  __shared__ float rres;
  const int b = blockIdx.x;
  const int tid = threadIdx.x;
  const int wid = tid >> 6, lane = tid & 63;
  float s[4];
  float mx = -1e30f;
#pragma unroll
  for (int p = 0; p < 4; ++p) {
    s[p] = w[b * NT + tid + p * 1024];
    mx = fmaxf(mx, s[p]);
  }
#pragma unroll
  for (int d = 32; d >= 1; d >>= 1) mx = fmaxf(mx, __shfl_xor(mx, d, 64));
  if (lane == 0) rtmp[wid] = mx;
  __syncthreads();
  if (tid == 0) {
    float mm = rtmp[0];
#pragma unroll
    for (int i = 1; i < 16; ++i) mm = fmaxf(mm, rtmp[i]);
    rres = mm;
  }
  __syncthreads();
  mx = rres;
  float sm = 0.f;
#pragma unroll
  for (int p = 0; p < 4; ++p) {
    int i = tid + p * 1024;
    float e = __expf(s[p] - mx);
    wsv[i] = e;
    asv[i] = 0.f;
    sm += e;
  }
#pragma unroll
  for (int d = 32; d >= 1; d >>= 1) sm += __shfl_xor(sm, d, 64);
  if (lane == 0) rtmp[wid] = sm;
  __syncthreads();
  if (tid == 0) {
    float tt = 0.f;
#pragma unroll
    for (int i = 0; i < 16; ++i) tt += rtmp[i];
    rres = tt;
  }
  __syncthreads();
  const float inv = 1.0f / rres;

  for (int j = tid; j < NE; j += 1024) {
    int ss = esrc[b * NE + j];
    int dd = edst[b * NE + j];
    if (dd != ss + 1) atomicAdd(&asv[dd], wsv[ss]);
  }
  __syncthreads();
#pragma unroll
  for (int p = 0; p < 4; ++p) {
    int i = tid + p * 1024;
    w[b * NT + i] = 0.1f * asv[i] * inv;
  }
}

extern "C" void kernel_launch(void* const* d_in, const int* in_sizes, int n_in,
                              void* d_out, int out_size, void* d_ws, size_t ws_size,
                              hipStream_t stream) {
  const float* hidden = (const float*)d_in[0];
  const float* enc    = (const float*)d_in[1];
  const int*   esrc   = (const int*)d_in[2];
  const int*   edst   = (const int*)d_in[3];
  const float* Wattn  = (const float*)d_in[4];
  const float* battn  = (const float*)d_in[5];
  const float* vvec   = (const float*)d_in[6];
  float* out = (float*)d_out;        // scores scratch, then final [B,1,T]
  float* cvec = (float*)d_ws;        // 32*512 floats = 64 KB

  precompute_c<<<256, 256, 0, stream>>>(hidden, Wattn, battn, cvec);
  score_gemm<<<(NB * NT) / 64, 256, 0, stream>>>(enc, Wattn, cvec, vvec, out);
  softmax_scatter<<<NB, 1024, 0, stream>>>(out, esrc, edst);
}